// Round 2
// baseline (436.868 us; speedup 1.0000x reference)
//
#include <hip/hip_runtime.h>

// KV cache update, token-gen path.
// Shapes: L=2, B=4, H=8, M=4096, D=128, fp32.
// out[2, L, B, H, M, D]: out[0]=k_caches, out[1]=v_caches, with row
// m == position_ids[b] replaced by latest_{k,v}[l,b,h,0,:] for every (l,b,h).
//
// Implementation: two D2D memcpys (AMD tuned blit path, ~6.5+ TB/s) followed
// by a tiny scatter kernel overwriting the 128 target rows (64 KB total).
// Stream ordering makes the scatter land after the copies.

constexpr int Ln = 2, Bn = 4, Hn = 8, Mn = 4096, Dn = 128;
constexpr long N_ELEM = (long)Ln * Bn * Hn * Mn * Dn;   // 33,554,432 per cache
constexpr size_t CACHE_BYTES = (size_t)N_ELEM * 4;      // 134,217,728 B

// 2 tensors (k,v) * L*B*H = 128 rows, D/4 = 32 float4 per row -> 4096 threads.
__global__ __launch_bounds__(256) void kv_scatter_kernel(
    const float4* __restrict__ lk,   // latest_k  (L,B,H,1,D)
    const float4* __restrict__ lv,   // latest_v
    const int*    __restrict__ pos,  // position_ids (B,1)
    float4*       __restrict__ out)  // (2,L,B,H,M,D)
{
    int j = blockIdx.x * 256 + threadIdx.x;   // 0 .. 4095
    int lane = j & 31;           // D/4 = 32
    int t    = j >> 5;           // row id: 0 .. 127
    int h    = t & (Hn - 1);
    int t2   = t >> 3;
    int b    = t2 & (Bn - 1);
    int t3   = t2 >> 2;
    int l    = t3 & 1;
    int kv   = t3 >> 1;          // 0 = k, 1 = v

    const float4* lsrc = kv ? lv : lk;
    float4 val = lsrc[((l * Bn + b) * Hn + h) * (Dn / 4) + lane];

    int p = pos[b];
    long row = ((((long)kv * Ln + l) * Bn + b) * Hn + h) * Mn + p;
    out[row * (Dn / 4) + lane] = val;
}

extern "C" void kernel_launch(void* const* d_in, const int* in_sizes, int n_in,
                              void* d_out, int out_size, void* d_ws, size_t ws_size,
                              hipStream_t stream) {
    const void* kc  = d_in[0];
    const void* vc  = d_in[1];
    const float4* lk  = (const float4*)d_in[2];
    const float4* lv  = (const float4*)d_in[3];
    const int*    pos = (const int*)d_in[4];
    // d_in[5] = seq_len (unused: position_ids < seq_len by construction,
    // and the scatter+concat is equivalent to a direct row overwrite).

    char* out = (char*)d_out;

    // Bulk copy: out[0] = k_caches, out[1] = v_caches.
    hipMemcpyAsync(out,               kc, CACHE_BYTES, hipMemcpyDeviceToDevice, stream);
    hipMemcpyAsync(out + CACHE_BYTES, vc, CACHE_BYTES, hipMemcpyDeviceToDevice, stream);

    // Sparse overwrite of 128 rows (runs after copies via stream order).
    kv_scatter_kernel<<<16, 256, 0, stream>>>(lk, lv, pos, (float4*)d_out);
}